// Round 12
// baseline (144.288 us; speedup 1.0000x reference)
//
#include <hip/hip_runtime.h>
#include <hip/hip_cooperative_groups.h>
#include <cstdint>
#include <cstddef>

namespace cg = cooperative_groups;

// ---------------------------------------------------------------------------
// Problem constants
// ---------------------------------------------------------------------------
#define BB 2
#define PP 4
#define CC 3
#define HWSZ 65536            // H*W
#define BGH 2764
#define BGW 3856
#define NTAO 27               // 3 lifes x 9 linspace points
#define X4_SIZE (BB*PP*HWSZ)              // 524288
#define TAO_OFF X4_SIZE
#define TAO_SIZE (BB*NTAO*HWSZ)           // 3538944
#define OUT2_OFF (TAO_OFF + TAO_SIZE)     // 4063232
#define NPK 24                            // poisson draws shipped (P(>24)~1e-16)
#define NBLK_F 1024                       // fused kernel blocks (coop-safe)

// ---------------------------------------------------------------------------
// rotl via v_alignbit_b32
// ---------------------------------------------------------------------------
__host__ __device__ inline uint32_t rotl32(uint32_t x, int r) {
#ifdef __HIP_DEVICE_COMPILE__
  return __builtin_amdgcn_alignbit(x, x, 32 - r);
#else
  return (x << r) | (x >> (32 - r));
#endif
}

// ---------------------------------------------------------------------------
// Threefry-2x32-20 (jax partitionable mode — verified r2..r11)
// ---------------------------------------------------------------------------
__host__ __device__ inline void tf2x32(uint32_t k0, uint32_t k1,
                                       uint32_t x0, uint32_t x1,
                                       uint32_t& o0, uint32_t& o1) {
  uint32_t ks2 = k0 ^ k1 ^ 0x1BD11BDAu;
  x0 += k0; x1 += k1;
#define TF_RND(r) { x0 += x1; x1 = rotl32(x1, r); x1 ^= x0; }
  TF_RND(13) TF_RND(15) TF_RND(26) TF_RND(6)
  x0 += k1;  x1 += ks2 + 1u;
  TF_RND(17) TF_RND(29) TF_RND(16) TF_RND(24)
  x0 += ks2; x1 += k0 + 2u;
  TF_RND(13) TF_RND(15) TF_RND(26) TF_RND(6)
  x0 += k0;  x1 += k1 + 3u;
  TF_RND(17) TF_RND(29) TF_RND(16) TF_RND(24)
  x0 += k1;  x1 += ks2 + 4u;
  TF_RND(13) TF_RND(15) TF_RND(26) TF_RND(6)
  x0 += ks2; x1 += k0 + 5u;
#undef TF_RND
  o0 = x0; o1 = x1;
}

__host__ __device__ inline uint32_t bits32(uint32_t k0, uint32_t k1, uint32_t e) {
  uint32_t o0, o1;
  tf2x32(k0, k1, 0u, e, o0, o1);
  return o0 ^ o1;
}

// partitionable split: subkey i = RAW pair threefry(key, (0,i))
static void jax_split(uint32_t k0, uint32_t k1, int n, uint32_t (*keys)[2]) {
  for (int i = 0; i < n; ++i)
    tf2x32(k0, k1, 0u, (uint32_t)i, keys[i][0], keys[i][1]);
}

__host__ __device__ inline float u01(uint32_t bits) {
  uint32_t fb = (bits >> 9) | 0x3F800000u;
  return __builtin_bit_cast(float, fb) - 1.0f;
}

// ---------------------------------------------------------------------------
// erfinv (Giles poly == XLA ErfInv32), fast transcendentals
// ---------------------------------------------------------------------------
__device__ inline float erfinv_f(float x) {
  float w = -__logf(fmaf(-x, x, 1.0f));
  float p;
  if (w < 5.0f) {
    w = w - 2.5f;
    p = 2.81022636e-08f;
    p = fmaf(p, w, 3.43273939e-07f);
    p = fmaf(p, w, -3.5233877e-06f);
    p = fmaf(p, w, -4.39150654e-06f);
    p = fmaf(p, w, 0.00021858087f);
    p = fmaf(p, w, -0.00125372503f);
    p = fmaf(p, w, -0.00417768164f);
    p = fmaf(p, w, 0.246640727f);
    p = fmaf(p, w, 1.50140941f);
  } else {
    w = __builtin_amdgcn_sqrtf(w) - 3.0f;
    p = -0.000200214257f;
    p = fmaf(p, w, 0.000100950558f);
    p = fmaf(p, w, 0.00134934322f);
    p = fmaf(p, w, -0.00367342844f);
    p = fmaf(p, w, 0.00573950773f);
    p = fmaf(p, w, -0.0076224613f);
    p = fmaf(p, w, 0.00943887047f);
    p = fmaf(p, w, 1.00167406f);
    p = fmaf(p, w, 2.83297682f);
  }
  return p * x;
}

__device__ inline float normal_e(uint32_t k0, uint32_t k1, uint32_t e) {
  float f = u01(bits32(k0, k1, e));
  const float LO = -0.99999994f;
  float u = fmaxf(LO, fmaf(f, 2.0f, LO));
  return 1.41421356237f * erfinv_f(u);
}

struct PCParams {
  uint32_t kn0, kn1;        // k_norm
  uint32_t kb0, kb1;        // k_bgn
  uint32_t s1[NPK * 2];     // poisson chain subkeys for k_p1
  uint32_t s2[NPK * 2];     // poisson chain subkeys for k_p2
  float bg1[8], bg2[8];
  int idx;
};

// ---------------------------------------------------------------------------
// Product-form Knuth count, granularity 2 (verified r11): no v_log in loop.
// ---------------------------------------------------------------------------
__device__ inline int pk_count2(const uint32_t* __restrict__ sk,
                                uint32_t e, float T) {
  float P = 1.0f;
  int cnt = 0;
#pragma clang loop unroll(disable)
  for (int i = 0; i < NPK; i += 2) {
    if (!__any(P > T)) break;
    float u0 = u01(bits32(sk[2*i],   sk[2*i+1], e));
    float u1 = u01(bits32(sk[2*i+2], sk[2*i+3], e));
    float P0 = P * u0;
    float P1 = P0 * u1;
    cnt += (P0 > T) ? 1 : 0;
    cnt += (P1 > T) ? 1 : 0;
    P = P1;
  }
  return cnt;
}

// ---------------------------------------------------------------------------
// Gaussian ladder (3 exps instead of 9). Accumulates tg9, returns decay.
// ---------------------------------------------------------------------------
__device__ inline float decay_pc(uint32_t kl0, uint32_t kl1, uint32_t ks0,
                                 uint32_t ks1, uint32_t e,
                                 const float (*et)[4], int p, float* tg9) {
  float ul = u01(bits32(kl0, kl1, e));
  float us = u01(bits32(ks0, ks1, e));
  float d0 = -40.0f - (ul - 0.5f) * 12.0f;   // tao0 - Lr (life cancels)
  float sr = fmaf(us - 0.5f, 0.6f, 6.0f);
  float inv = __builtin_amdgcn_rcpf(2.0f * sr * sr);
  float q[9];
  float A  = __expf(-20.0f * inv * d0);
  float Bm = __expf(-100.0f * inv);
  float B2 = Bm * Bm;
  q[0] = __expf(-(d0 * d0) * inv);
  float m = A * Bm;
  float s = q[0];
#pragma unroll
  for (int j = 1; j < 9; ++j) {
    q[j] = q[j - 1] * m;
    m *= B2;
    s += q[j];
  }
  float rs = __builtin_amdgcn_rcpf(s);
  float dec = 0.0f;
#pragma unroll
  for (int j = 0; j < 9; ++j) {
    float wn = q[j] * rs;
    tg9[j] += wn;
    dec = fmaf(et[j][p], wn, dec);
  }
  return dec;
}

// ---------------------------------------------------------------------------
// Fused kernel (cooperative): phase 1 = decay/tao_gt/x2 (x2 stays in regs),
// grid sync + global max, phase 2 = noise + patch -> x4.
// 1024 blocks x 256; each block does 2 vblks (r5 kA geometry per vblk).
// ---------------------------------------------------------------------------
__global__ __launch_bounds__(256, 4) void kFused(
    const float* __restrict__ x, const float* __restrict__ t,
    const float* __restrict__ ratio, const float* __restrict__ life,
    const float* __restrict__ inten, const float* __restrict__ bgf,
    float* __restrict__ out, float* __restrict__ bmax,
    uint32_t kl0, uint32_t kl1, uint32_t ks0, uint32_t ks1, PCParams pc) {
  __shared__ float et_s[NTAO][4];
  __shared__ float inten_s[3];
  __shared__ float tg_lds[4][9][64];
  __shared__ float bmax_s[4];
  __shared__ float red_s[4];
  __shared__ float mx_s;
  const int tid = threadIdx.x;
  if (tid < NTAO * 4) {
    int j = tid >> 2, p = tid & 3;
    float tao = life[j / 9] + (-40.0f + 10.0f * (float)(j % 9));
    float Tp = fmaxf(t[p] * ratio[p] * 1000.0f, 0.0f);
    et_s[j][p] = expf((-Tp) / tao);   // prologue only: libm accuracy
  }
  if (tid < 3) inten_s[tid] = inten[tid];
  __syncthreads();

  const int p = tid >> 6;               // wave id = p
  const int lane = tid & 63;

  // ---- phase 1: decay weights, tao_gt, x2 (kept in registers) ----
  float accv0 = 0.0f, accv1 = 0.0f;
#pragma unroll
  for (int g2 = 0; g2 < 2; ++g2) {
    const int vblk = blockIdx.x * 2 + g2;
    const int b = vblk >> 10;
    const int hwg = vblk & 1023;
    const int hw = hwg * 64 + lane;

    float acc = 0.0f;
    for (int c = 0; c < 3; ++c) {
      float tg9[9];
#pragma unroll
      for (int j = 0; j < 9; ++j) tg9[j] = 0.0f;

      const uint32_t e = (uint32_t)((((b * 4 + p) * 3 + c) << 16) + hw);
      float dec = decay_pc(kl0, kl1, ks0, ks1, e,
                           (const float(*)[4])&et_s[c * 9], p, tg9);
      acc = fmaf(x[e] * dec, inten_s[c], acc);

#pragma unroll
      for (int j = 0; j < 9; ++j) tg_lds[p][j][lane] = tg9[j];
      __syncthreads();
      for (int jj = p; jj < 9; jj += 4) {
        float s = ((tg_lds[0][jj][lane] + tg_lds[1][jj][lane]) +
                   (tg_lds[2][jj][lane] + tg_lds[3][jj][lane]));
        out[TAO_OFF + ((b * NTAO + c * 9 + jj) << 16) + hw] = s * 0.25f;
      }
      __syncthreads();
    }
    if (g2 == 0) accv0 = acc; else accv1 = acc;
  }

  // block max over both vblks (x2 >= 0), no atomics
  {
    float m = fmaxf(accv0, accv1);
#pragma unroll
    for (int off = 32; off; off >>= 1) m = fmaxf(m, __shfl_xor(m, off));
    if (lane == 0) bmax_s[p] = m;
    __syncthreads();
    if (tid == 0)
      bmax[blockIdx.x] = fmaxf(fmaxf(bmax_s[0], bmax_s[1]),
                               fmaxf(bmax_s[2], bmax_s[3]));
  }

  // ---- grid-wide sync: all bmax entries visible ----
  cg::this_grid().sync();

  // global max from bmax[1024]
  {
    float m = fmaxf(fmaxf(bmax[tid], bmax[tid + 256]),
                    fmaxf(bmax[tid + 512], bmax[tid + 768]));
#pragma unroll
    for (int off = 32; off; off >>= 1) m = fmaxf(m, __shfl_xor(m, off));
    if ((tid & 63) == 0) red_s[tid >> 6] = m;
    __syncthreads();
    if (tid == 0)
      mx_s = fmaxf(fmaxf(red_s[0], red_s[1]), fmaxf(red_s[2], red_s[3]));
    __syncthreads();
  }
  const float mx = mx_s;

  if (blockIdx.x == 0 && tid < 8)
    out[OUT2_OFF + tid] = (tid < 4) ? t[tid] * ratio[tid] : ratio[tid - 4];

  // ---- phase 2: noise + background patch -> x4 (x2 from registers) ----
#pragma unroll
  for (int g2 = 0; g2 < 2; ++g2) {
    const int vblk = blockIdx.x * 2 + g2;
    const int b = vblk >> 10;
    const int hwg = vblk & 1023;
    const int hw = hwg * 64 + lane;
    const int bp = b * 4 + p;
    const int e = (bp << 16) + hw;
    const float x2 = (g2 == 0) ? accv0 : accv1;

    const int r = hw >> 8;
    const int cc = hw & 255;
    const int row = pc.idx + r;
    const float bg = bgf[(p * BGH + row) * BGW + cc];   // panel p in [0,4)

    const uint32_t ebg = (uint32_t)((bp * BGH + row) * BGW + cc);
    float nb = normal_e(pc.kb0, pc.kb1, ebg);
    float n  = normal_e(pc.kn0, pc.kn1, (uint32_t)e);
    float patch = (bg * pc.bg1[bp] + nb * pc.bg2[bp]) * 0.1f;

    const float xm = x2 * __builtin_amdgcn_rcpf(mx + 0.0001f);
    float n_int = fmaf(xm, 5.0f, n);

    const float lam1 = fmaxf(xm, 0.0f);
    const bool z1 = !(lam1 > 0.0f);
    float pi = 0.0f;
    if (!z1) {
      float T1 = __expf(-lam1);
      pi = (float)pk_count2(pc.s1, (uint32_t)e, T1);
    }
    const float T2 = 0.13533528f;        // e^-2
    float po = (float)pk_count2(pc.s2, (uint32_t)e, T2);

    float x3 = ((n_int + pi) + po) + x2;
    float v = x3 + patch;
    v = fminf(fmaxf(v, 0.0f), 255.0f);
    out[e] = v * (1.0f / 255.0f);
  }
}

// ---------------------------------------------------------------------------
// Host
// ---------------------------------------------------------------------------
extern "C" void kernel_launch(void* const* d_in, const int* in_sizes, int n_in,
                              void* d_out, int out_size, void* d_ws, size_t ws_size,
                              hipStream_t stream) {
  const float* x     = (const float*)d_in[0];
  const float* t     = (const float*)d_in[1];
  const float* ratio = (const float*)d_in[2];
  const float* life  = (const float*)d_in[3];
  const float* inten = (const float*)d_in[4];
  const float* bgf   = (const float*)d_in[5];
  float* out = (float*)d_out;
  float* bmax = (float*)d_ws;            // [0, 1024): per-block maxes

  // key(42) = (0,42) -> 9 subkeys:
  // k_life, k_sig, k_norm, k_p1, k_p2, k_bg1, k_bg2, k_bgn, k_idx
  uint32_t sk[9][2];
  jax_split(0u, 42u, 9, sk);

  PCParams pc;
  pc.kn0 = sk[2][0]; pc.kn1 = sk[2][1];
  pc.kb0 = sk[7][0]; pc.kb1 = sk[7][1];

  {
    uint32_t r0 = sk[3][0], r1 = sk[3][1];
    for (int i = 0; i < NPK; ++i) {
      uint32_t two[2][2];
      jax_split(r0, r1, 2, two);
      pc.s1[2*i] = two[1][0]; pc.s1[2*i+1] = two[1][1];
      r0 = two[0][0]; r1 = two[0][1];
    }
    r0 = sk[4][0]; r1 = sk[4][1];
    for (int i = 0; i < NPK; ++i) {
      uint32_t two[2][2];
      jax_split(r0, r1, 2, two);
      pc.s2[2*i] = two[1][0]; pc.s2[2*i+1] = two[1][1];
      r0 = two[0][0]; r1 = two[0][1];
    }
  }

  for (uint32_t i = 0; i < 8; ++i) {
    pc.bg1[i] = u01(bits32(sk[5][0], sk[5][1], i)) * 0.5f + 0.5f;
    pc.bg2[i] = u01(bits32(sk[6][0], sk[6][1], i)) * 0.5f + 0.5f;
  }

  // idx = randint(k_idx, (), 0, 9): exact jax double-word algorithm
  {
    uint32_t hi = bits32(sk[8][0], sk[8][1], 0u);
    uint32_t lo = bits32(sk[8][0], sk[8][1], 1u);
    const uint32_t span = 9u;
    uint32_t mult = (65536u % span);
    mult = (mult * mult) % span;
    uint32_t off = ((hi % span) * mult + (lo % span)) % span;
    pc.idx = (int)off;
  }

  uint32_t kl0 = sk[0][0], kl1 = sk[0][1], ks0 = sk[1][0], ks1 = sk[1][1];
  void* args[] = {
    (void*)&x, (void*)&t, (void*)&ratio, (void*)&life, (void*)&inten,
    (void*)&bgf, (void*)&out, (void*)&bmax,
    (void*)&kl0, (void*)&kl1, (void*)&ks0, (void*)&ks1, (void*)&pc
  };
  hipLaunchCooperativeKernel((const void*)kFused, dim3(NBLK_F), dim3(256),
                             args, 0, stream);
}

// Round 13
// 34.718 us; speedup vs baseline: 4.1560x; 4.1560x over previous
//
#include <hip/hip_runtime.h>
#include <cstdint>
#include <cstddef>

// ---------------------------------------------------------------------------
// Problem constants
// ---------------------------------------------------------------------------
#define BB 2
#define PP 4
#define CC 3
#define HWSZ 65536            // H*W
#define BGH 2764
#define BGW 3856
#define NTAO 27               // 3 lifes x 9 linspace points
#define X4_SIZE (BB*PP*HWSZ)              // 524288
#define TAO_OFF X4_SIZE
#define TAO_SIZE (BB*NTAO*HWSZ)           // 3538944
#define OUT2_OFF (TAO_OFF + TAO_SIZE)     // 4063232
#define NPK 24                            // poisson draws shipped (P(>24)~1e-16)
#define NBLK_A 2048                       // kA blocks
#define NBLK_C 1024                       // kC blocks (2 elements/thread)

// ---------------------------------------------------------------------------
// rotl via v_alignbit_b32
// ---------------------------------------------------------------------------
__host__ __device__ inline uint32_t rotl32(uint32_t x, int r) {
#ifdef __HIP_DEVICE_COMPILE__
  return __builtin_amdgcn_alignbit(x, x, 32 - r);
#else
  return (x << r) | (x >> (32 - r));
#endif
}

// ---------------------------------------------------------------------------
// Threefry-2x32-20 (jax partitionable mode — verified r2..r12)
// ---------------------------------------------------------------------------
__host__ __device__ inline void tf2x32(uint32_t k0, uint32_t k1,
                                       uint32_t x0, uint32_t x1,
                                       uint32_t& o0, uint32_t& o1) {
  uint32_t ks2 = k0 ^ k1 ^ 0x1BD11BDAu;
  x0 += k0; x1 += k1;
#define TF_RND(r) { x0 += x1; x1 = rotl32(x1, r); x1 ^= x0; }
  TF_RND(13) TF_RND(15) TF_RND(26) TF_RND(6)
  x0 += k1;  x1 += ks2 + 1u;
  TF_RND(17) TF_RND(29) TF_RND(16) TF_RND(24)
  x0 += ks2; x1 += k0 + 2u;
  TF_RND(13) TF_RND(15) TF_RND(26) TF_RND(6)
  x0 += k0;  x1 += k1 + 3u;
  TF_RND(17) TF_RND(29) TF_RND(16) TF_RND(24)
  x0 += k1;  x1 += ks2 + 4u;
  TF_RND(13) TF_RND(15) TF_RND(26) TF_RND(6)
  x0 += ks2; x1 += k0 + 5u;
#undef TF_RND
  o0 = x0; o1 = x1;
}

__host__ __device__ inline uint32_t bits32(uint32_t k0, uint32_t k1, uint32_t e) {
  uint32_t o0, o1;
  tf2x32(k0, k1, 0u, e, o0, o1);
  return o0 ^ o1;
}

// partitionable split: subkey i = RAW pair threefry(key, (0,i))
static void jax_split(uint32_t k0, uint32_t k1, int n, uint32_t (*keys)[2]) {
  for (int i = 0; i < n; ++i)
    tf2x32(k0, k1, 0u, (uint32_t)i, keys[i][0], keys[i][1]);
}

__host__ __device__ inline float u01(uint32_t bits) {
  uint32_t fb = (bits >> 9) | 0x3F800000u;
  return __builtin_bit_cast(float, fb) - 1.0f;
}

// ---------------------------------------------------------------------------
// erfinv (Giles poly == XLA ErfInv32), fast transcendentals
// ---------------------------------------------------------------------------
__device__ inline float erfinv_f(float x) {
  float w = -__logf(fmaf(-x, x, 1.0f));
  float p;
  if (w < 5.0f) {
    w = w - 2.5f;
    p = 2.81022636e-08f;
    p = fmaf(p, w, 3.43273939e-07f);
    p = fmaf(p, w, -3.5233877e-06f);
    p = fmaf(p, w, -4.39150654e-06f);
    p = fmaf(p, w, 0.00021858087f);
    p = fmaf(p, w, -0.00125372503f);
    p = fmaf(p, w, -0.00417768164f);
    p = fmaf(p, w, 0.246640727f);
    p = fmaf(p, w, 1.50140941f);
  } else {
    w = __builtin_amdgcn_sqrtf(w) - 3.0f;
    p = -0.000200214257f;
    p = fmaf(p, w, 0.000100950558f);
    p = fmaf(p, w, 0.00134934322f);
    p = fmaf(p, w, -0.00367342844f);
    p = fmaf(p, w, 0.00573950773f);
    p = fmaf(p, w, -0.0076224613f);
    p = fmaf(p, w, 0.00943887047f);
    p = fmaf(p, w, 1.00167406f);
    p = fmaf(p, w, 2.83297682f);
  }
  return p * x;
}

__device__ inline float normal_e(uint32_t k0, uint32_t k1, uint32_t e) {
  float f = u01(bits32(k0, k1, e));
  const float LO = -0.99999994f;
  float u = fmaxf(LO, fmaf(f, 2.0f, LO));
  return 1.41421356237f * erfinv_f(u);
}

struct PCParams {
  uint32_t kn0, kn1;        // k_norm
  uint32_t kb0, kb1;        // k_bgn
  uint32_t s1[NPK * 2];     // poisson chain subkeys for k_p1
  uint32_t s2[NPK * 2];     // poisson chain subkeys for k_p2
  float bg1[8], bg2[8];
  int idx;
};

// ---------------------------------------------------------------------------
// Gaussian ladder (3 exps instead of 9). Accumulates tg9, returns decay.
// ---------------------------------------------------------------------------
__device__ inline float decay_pc(uint32_t kl0, uint32_t kl1, uint32_t ks0,
                                 uint32_t ks1, uint32_t e,
                                 const float (*et)[4], int p, float* tg9) {
  float ul = u01(bits32(kl0, kl1, e));
  float us = u01(bits32(ks0, ks1, e));
  float d0 = -40.0f - (ul - 0.5f) * 12.0f;   // tao0 - Lr (life cancels)
  float sr = fmaf(us - 0.5f, 0.6f, 6.0f);
  float inv = __builtin_amdgcn_rcpf(2.0f * sr * sr);
  float q[9];
  float A  = __expf(-20.0f * inv * d0);
  float Bm = __expf(-100.0f * inv);
  float B2 = Bm * Bm;
  q[0] = __expf(-(d0 * d0) * inv);
  float m = A * Bm;
  float s = q[0];
#pragma unroll
  for (int j = 1; j < 9; ++j) {
    q[j] = q[j - 1] * m;
    m *= B2;
    s += q[j];
  }
  float rs = __builtin_amdgcn_rcpf(s);
  float dec = 0.0f;
#pragma unroll
  for (int j = 0; j < 9; ++j) {
    float wn = q[j] * rs;
    tg9[j] += wn;
    dec = fmaf(et[j][p], wn, dec);
  }
  return dec;
}

// ---------------------------------------------------------------------------
// Kernel A (r11-proven, VALU-saturated at 9.8us body): 2048 blocks x 256.
// ---------------------------------------------------------------------------
__global__ __launch_bounds__(256) void kA(
    const float* __restrict__ x, const float* __restrict__ t,
    const float* __restrict__ ratio, const float* __restrict__ life,
    const float* __restrict__ inten, float* __restrict__ out,
    float* __restrict__ bmax,
    uint32_t kl0, uint32_t kl1, uint32_t ks0, uint32_t ks1) {
  __shared__ float et_s[NTAO][4];
  __shared__ float inten_s[3];
  __shared__ float tg_lds[4][9][64];
  __shared__ float bmax_s[4];
  const int tid = threadIdx.x;
  if (tid < NTAO * 4) {
    int j = tid >> 2, p = tid & 3;
    float tao = life[j / 9] + (-40.0f + 10.0f * (float)(j % 9));
    float Tp = fmaxf(t[p] * ratio[p] * 1000.0f, 0.0f);
    et_s[j][p] = expf((-Tp) / tao);
  }
  if (tid < 3) inten_s[tid] = inten[tid];
  __syncthreads();

  const int blk = blockIdx.x;
  const int b = blk >> 10;
  const int hwg = blk & 1023;
  const int p = tid >> 6;
  const int lane = tid & 63;
  const int hw = hwg * 64 + lane;

  float acc = 0.0f;

  for (int c = 0; c < 3; ++c) {
    float tg9[9];
#pragma unroll
    for (int j = 0; j < 9; ++j) tg9[j] = 0.0f;

    const uint32_t e = (uint32_t)((((b * 4 + p) * 3 + c) << 16) + hw);
    float dec = decay_pc(kl0, kl1, ks0, ks1, e,
                         (const float(*)[4])&et_s[c * 9], p, tg9);
    acc = fmaf(x[e] * dec, inten_s[c], acc);

#pragma unroll
    for (int j = 0; j < 9; ++j) tg_lds[p][j][lane] = tg9[j];
    __syncthreads();
    for (int jj = p; jj < 9; jj += 4) {
      float s = ((tg_lds[0][jj][lane] + tg_lds[1][jj][lane]) +
                 (tg_lds[2][jj][lane] + tg_lds[3][jj][lane]));
      out[TAO_OFF + ((b * NTAO + c * 9 + jj) << 16) + hw] = s * 0.25f;
    }
    __syncthreads();
  }

  out[((b * 4 + p) << 16) + hw] = acc;   // x2 staged in the x4 slot

  float m = acc;
#pragma unroll
  for (int off = 32; off; off >>= 1) m = fmaxf(m, __shfl_xor(m, off));
  if (lane == 0) bmax_s[p] = m;
  __syncthreads();
  if (tid == 0)
    bmax[blk] = fmaxf(fmaxf(bmax_s[0], bmax_s[1]),
                      fmaxf(bmax_s[2], bmax_s[3]));
}

// ---------------------------------------------------------------------------
// Kernel C: 2 elements/thread, Poisson as a 4-task per-lane state machine
// (task = element x chain). Same u-sequence/products as r11 -> bit-identical
// counts; only scheduling changes (wave-max amortized over 4 tasks).
// Subkeys in LDS (draw index is lane-divergent).
// ---------------------------------------------------------------------------
__global__ __launch_bounds__(256) void kC(
    const float* __restrict__ bgf, const float* __restrict__ t,
    const float* __restrict__ ratio, float* __restrict__ out,
    const float* __restrict__ bmax, PCParams pc) {
  __shared__ float red_s[4];
  __shared__ float mx_s;
  __shared__ uint32_t keys_lds[2 * NPK * 2];   // [chain][i][2]
  const int tid = threadIdx.x;

  // stage poisson subkeys to LDS
  if (tid < NPK * 2) {
    keys_lds[tid] = pc.s1[tid];
    keys_lds[NPK * 2 + tid] = pc.s2[tid];
  }

  // global max from bmax[2048]
  float m = 0.0f;
#pragma unroll
  for (int k = 0; k < 8; ++k) m = fmaxf(m, bmax[tid + 256 * k]);
#pragma unroll
  for (int off = 32; off; off >>= 1) m = fmaxf(m, __shfl_xor(m, off));
  if ((tid & 63) == 0) red_s[tid >> 6] = m;
  __syncthreads();
  if (tid == 0)
    mx_s = fmaxf(fmaxf(red_s[0], red_s[1]), fmaxf(red_s[2], red_s[3]));
  __syncthreads();
  const float mx = mx_s;
  const float rmx = __builtin_amdgcn_rcpf(mx + 0.0001f);

  if (blockIdx.x == 0 && tid < 8)
    out[OUT2_OFF + tid] = (tid < 4) ? t[tid] * ratio[tid] : ratio[tid - 4];

  const int gid = blockIdx.x * 256 + tid;       // [0, 262144)
  const int e0 = gid;                           // bp in [0,4)
  const int e1 = gid + X4_SIZE / 2;             // bp in [4,8)

  // per-element setup
  const int bp0 = e0 >> 16, bp1 = e1 >> 16;
  const int hw0 = e0 & 0xFFFF, hw1 = e1 & 0xFFFF;
  const int r0 = hw0 >> 8, cc0 = hw0 & 255;
  const int r1 = hw1 >> 8, cc1 = hw1 & 255;
  const int row0 = pc.idx + r0, row1 = pc.idx + r1;
  const int pp0 = bp0 & 3, pp1 = bp1 & 3;

  const float x2_0 = out[e0];
  const float x2_1 = out[e1];
  const float bg0 = bgf[(pp0 * BGH + row0) * BGW + cc0];
  const float bg1v = bgf[(pp1 * BGH + row1) * BGW + cc1];

  const uint32_t ebg0 = (uint32_t)((bp0 * BGH + row0) * BGW + cc0);
  const uint32_t ebg1 = (uint32_t)((bp1 * BGH + row1) * BGW + cc1);
  float nb0 = normal_e(pc.kb0, pc.kb1, ebg0);
  float nb1 = normal_e(pc.kb0, pc.kb1, ebg1);
  float n0  = normal_e(pc.kn0, pc.kn1, (uint32_t)e0);
  float n1  = normal_e(pc.kn0, pc.kn1, (uint32_t)e1);
  float patch0 = (bg0  * pc.bg1[bp0] + nb0 * pc.bg2[bp0]) * 0.1f;
  float patch1 = (bg1v * pc.bg1[bp1] + nb1 * pc.bg2[bp1]) * 0.1f;

  const float xm0 = x2_0 * rmx;
  const float xm1 = x2_1 * rmx;
  const float T2 = 0.13533528f;                 // e^-2
  const float T1_0 = __expf(-fmaxf(xm0, 0.0f)); // lam=0 -> T=1 -> count 0 (ref)
  const float T1_1 = __expf(-fmaxf(xm1, 0.0f));

  // ---- 4-task poisson state machine ----
  // task t: 0:(e0,chain1) 1:(e0,chain2) 2:(e1,chain1) 3:(e1,chain2)
  int tsk = 0, i = 0;
  float P = 1.0f;
  float T = T1_0;
  uint32_t cnts = 0;
#pragma clang loop unroll(disable)
  for (int guard = 0; guard < 4 * NPK + 4; ++guard) {
    bool active = (tsk < 4);
    if (!__any(active)) break;
    // key fetch from LDS: chain = tsk&1
    int kaddr = ((tsk & 1) * NPK + i) * 2;
    uint32_t key0 = keys_lds[kaddr];
    uint32_t key1 = keys_lds[kaddr + 1];
    uint32_t ee = (tsk < 2) ? (uint32_t)e0 : (uint32_t)e1;
    float u = u01(bits32(key0, key1, ee));
    float Pn = P * u;
    bool succ = active && (Pn > T);
    if (succ) cnts += (1u << (tsk * 8));
    bool advance = active && (!succ || i == NPK - 1);
    if (active) P = Pn;
    if (advance) {
      tsk += 1;
      i = 0;
      P = 1.0f;
      T = (tsk & 1) ? T2 : T1_1;
    } else if (active) {
      i += 1;
    }
  }

  const float pi0 = (float)(cnts & 255u);
  const float po0 = (float)((cnts >> 8) & 255u);
  const float pi1 = (float)((cnts >> 16) & 255u);
  const float po1 = (float)(cnts >> 24);

  // ---- epilogues ----
  {
    float n_int = fmaf(xm0, 5.0f, n0);
    float x3 = ((n_int + pi0) + po0) + x2_0;
    float v = x3 + patch0;
    v = fminf(fmaxf(v, 0.0f), 255.0f);
    out[e0] = v * (1.0f / 255.0f);
  }
  {
    float n_int = fmaf(xm1, 5.0f, n1);
    float x3 = ((n_int + pi1) + po1) + x2_1;
    float v = x3 + patch1;
    v = fminf(fmaxf(v, 0.0f), 255.0f);
    out[e1] = v * (1.0f / 255.0f);
  }
}

// ---------------------------------------------------------------------------
// Host
// ---------------------------------------------------------------------------
extern "C" void kernel_launch(void* const* d_in, const int* in_sizes, int n_in,
                              void* d_out, int out_size, void* d_ws, size_t ws_size,
                              hipStream_t stream) {
  const float* x     = (const float*)d_in[0];
  const float* t     = (const float*)d_in[1];
  const float* ratio = (const float*)d_in[2];
  const float* life  = (const float*)d_in[3];
  const float* inten = (const float*)d_in[4];
  const float* bgf   = (const float*)d_in[5];
  float* out = (float*)d_out;
  float* bmax = (float*)d_ws;            // [0, 2048): per-block maxes

  // key(42) = (0,42) -> 9 subkeys:
  // k_life, k_sig, k_norm, k_p1, k_p2, k_bg1, k_bg2, k_bgn, k_idx
  uint32_t sk[9][2];
  jax_split(0u, 42u, 9, sk);

  PCParams pc;
  pc.kn0 = sk[2][0]; pc.kn1 = sk[2][1];
  pc.kb0 = sk[7][0]; pc.kb1 = sk[7][1];

  {
    uint32_t r0 = sk[3][0], r1 = sk[3][1];
    for (int i = 0; i < NPK; ++i) {
      uint32_t two[2][2];
      jax_split(r0, r1, 2, two);
      pc.s1[2*i] = two[1][0]; pc.s1[2*i+1] = two[1][1];
      r0 = two[0][0]; r1 = two[0][1];
    }
    r0 = sk[4][0]; r1 = sk[4][1];
    for (int i = 0; i < NPK; ++i) {
      uint32_t two[2][2];
      jax_split(r0, r1, 2, two);
      pc.s2[2*i] = two[1][0]; pc.s2[2*i+1] = two[1][1];
      r0 = two[0][0]; r1 = two[0][1];
    }
  }

  for (uint32_t i = 0; i < 8; ++i) {
    pc.bg1[i] = u01(bits32(sk[5][0], sk[5][1], i)) * 0.5f + 0.5f;
    pc.bg2[i] = u01(bits32(sk[6][0], sk[6][1], i)) * 0.5f + 0.5f;
  }

  // idx = randint(k_idx, (), 0, 9): exact jax double-word algorithm
  {
    uint32_t hi = bits32(sk[8][0], sk[8][1], 0u);
    uint32_t lo = bits32(sk[8][0], sk[8][1], 1u);
    const uint32_t span = 9u;
    uint32_t mult = (65536u % span);
    mult = (mult * mult) % span;
    uint32_t off = ((hi % span) * mult + (lo % span)) % span;
    pc.idx = (int)off;
  }

  kA<<<NBLK_A, 256, 0, stream>>>(x, t, ratio, life, inten, out, bmax,
                                 sk[0][0], sk[0][1], sk[1][0], sk[1][1]);
  kC<<<NBLK_C, 256, 0, stream>>>(bgf, t, ratio, out, bmax, pc);
}

// Round 14
// 34.435 us; speedup vs baseline: 4.1901x; 1.0082x over previous
//
#include <hip/hip_runtime.h>
#include <cstdint>
#include <cstddef>

// ---------------------------------------------------------------------------
// Problem constants
// ---------------------------------------------------------------------------
#define BB 2
#define PP 4
#define CC 3
#define HWSZ 65536            // H*W
#define BGH 2764
#define BGW 3856
#define NTAO 27               // 3 lifes x 9 linspace points
#define X4_SIZE (BB*PP*HWSZ)              // 524288
#define TAO_OFF X4_SIZE
#define TAO_SIZE (BB*NTAO*HWSZ)           // 3538944
#define OUT2_OFF (TAO_OFF + TAO_SIZE)     // 4063232
#define NPK 24                            // poisson draws shipped (P(>24)~1e-16)
#define NBLK_A 2048                       // kA blocks
#define NBLK_C 1024                       // kC blocks (2 elements/thread)

// ---------------------------------------------------------------------------
// rotl via v_alignbit_b32
// ---------------------------------------------------------------------------
__host__ __device__ inline uint32_t rotl32(uint32_t x, int r) {
#ifdef __HIP_DEVICE_COMPILE__
  return __builtin_amdgcn_alignbit(x, x, 32 - r);
#else
  return (x << r) | (x >> (32 - r));
#endif
}

// ---------------------------------------------------------------------------
// Threefry-2x32-20 (jax partitionable mode — verified r2..r13)
// ---------------------------------------------------------------------------
__host__ __device__ inline void tf2x32(uint32_t k0, uint32_t k1,
                                       uint32_t x0, uint32_t x1,
                                       uint32_t& o0, uint32_t& o1) {
  uint32_t ks2 = k0 ^ k1 ^ 0x1BD11BDAu;
  x0 += k0; x1 += k1;
#define TF_RND(r) { x0 += x1; x1 = rotl32(x1, r); x1 ^= x0; }
  TF_RND(13) TF_RND(15) TF_RND(26) TF_RND(6)
  x0 += k1;  x1 += ks2 + 1u;
  TF_RND(17) TF_RND(29) TF_RND(16) TF_RND(24)
  x0 += ks2; x1 += k0 + 2u;
  TF_RND(13) TF_RND(15) TF_RND(26) TF_RND(6)
  x0 += k0;  x1 += k1 + 3u;
  TF_RND(17) TF_RND(29) TF_RND(16) TF_RND(24)
  x0 += k1;  x1 += ks2 + 4u;
  TF_RND(13) TF_RND(15) TF_RND(26) TF_RND(6)
  x0 += ks2; x1 += k0 + 5u;
#undef TF_RND
  o0 = x0; o1 = x1;
}

__host__ __device__ inline uint32_t bits32(uint32_t k0, uint32_t k1, uint32_t e) {
  uint32_t o0, o1;
  tf2x32(k0, k1, 0u, e, o0, o1);
  return o0 ^ o1;
}

// partitionable split: subkey i = RAW pair threefry(key, (0,i))
static void jax_split(uint32_t k0, uint32_t k1, int n, uint32_t (*keys)[2]) {
  for (int i = 0; i < n; ++i)
    tf2x32(k0, k1, 0u, (uint32_t)i, keys[i][0], keys[i][1]);
}

__host__ __device__ inline float u01(uint32_t bits) {
  uint32_t fb = (bits >> 9) | 0x3F800000u;
  return __builtin_bit_cast(float, fb) - 1.0f;
}

// ---------------------------------------------------------------------------
// erfinv (Giles poly == XLA ErfInv32), fast transcendentals
// ---------------------------------------------------------------------------
__device__ inline float erfinv_f(float x) {
  float w = -__logf(fmaf(-x, x, 1.0f));
  float p;
  if (w < 5.0f) {
    w = w - 2.5f;
    p = 2.81022636e-08f;
    p = fmaf(p, w, 3.43273939e-07f);
    p = fmaf(p, w, -3.5233877e-06f);
    p = fmaf(p, w, -4.39150654e-06f);
    p = fmaf(p, w, 0.00021858087f);
    p = fmaf(p, w, -0.00125372503f);
    p = fmaf(p, w, -0.00417768164f);
    p = fmaf(p, w, 0.246640727f);
    p = fmaf(p, w, 1.50140941f);
  } else {
    w = __builtin_amdgcn_sqrtf(w) - 3.0f;
    p = -0.000200214257f;
    p = fmaf(p, w, 0.000100950558f);
    p = fmaf(p, w, 0.00134934322f);
    p = fmaf(p, w, -0.00367342844f);
    p = fmaf(p, w, 0.00573950773f);
    p = fmaf(p, w, -0.0076224613f);
    p = fmaf(p, w, 0.00943887047f);
    p = fmaf(p, w, 1.00167406f);
    p = fmaf(p, w, 2.83297682f);
  }
  return p * x;
}

// NOTE: XLA's u = max(lo, f*2+lo) clamp is unreachable for f >= 0
// (fmaf(f,2,LO) >= LO, equality at f=0) — dropped, bit-identical.
__device__ inline float normal_e(uint32_t k0, uint32_t k1, uint32_t e) {
  float f = u01(bits32(k0, k1, e));
  const float LO = -0.99999994f;
  float u = fmaf(f, 2.0f, LO);
  return 1.41421356237f * erfinv_f(u);
}

struct PCParams {
  uint32_t kn0, kn1;        // k_norm
  uint32_t kb0, kb1;        // k_bgn
  uint32_t s1[NPK * 2];     // poisson chain subkeys for k_p1
  uint32_t s2[NPK * 2];     // poisson chain subkeys for k_p2
  float bg1[8], bg2[8];
  int idx;
};

// ---------------------------------------------------------------------------
// Gaussian ladder (3 exps instead of 9). Accumulates tg9, returns decay.
// ---------------------------------------------------------------------------
__device__ inline float decay_pc(uint32_t kl0, uint32_t kl1, uint32_t ks0,
                                 uint32_t ks1, uint32_t e,
                                 const float (*et)[4], int p, float* tg9) {
  float ul = u01(bits32(kl0, kl1, e));
  float us = u01(bits32(ks0, ks1, e));
  float d0 = -40.0f - (ul - 0.5f) * 12.0f;   // tao0 - Lr (life cancels)
  float sr = fmaf(us - 0.5f, 0.6f, 6.0f);
  float inv = __builtin_amdgcn_rcpf(2.0f * sr * sr);
  float q[9];
  float A  = __expf(-20.0f * inv * d0);
  float Bm = __expf(-100.0f * inv);
  float B2 = Bm * Bm;
  q[0] = __expf(-(d0 * d0) * inv);
  float m = A * Bm;
  float s = q[0];
#pragma unroll
  for (int j = 1; j < 9; ++j) {
    q[j] = q[j - 1] * m;
    m *= B2;
    s += q[j];
  }
  float rs = __builtin_amdgcn_rcpf(s);
  float dec = 0.0f;
#pragma unroll
  for (int j = 0; j < 9; ++j) {
    float wn = q[j] * rs;
    tg9[j] += wn;
    dec = fmaf(et[j][p], wn, dec);
  }
  return dec;
}

// ---------------------------------------------------------------------------
// Kernel A (r11-proven, VALU-saturated at 9.8us body): 2048 blocks x 256.
// ---------------------------------------------------------------------------
__global__ __launch_bounds__(256) void kA(
    const float* __restrict__ x, const float* __restrict__ t,
    const float* __restrict__ ratio, const float* __restrict__ life,
    const float* __restrict__ inten, float* __restrict__ out,
    float* __restrict__ bmax,
    uint32_t kl0, uint32_t kl1, uint32_t ks0, uint32_t ks1) {
  __shared__ float et_s[NTAO][4];
  __shared__ float inten_s[3];
  __shared__ float tg_lds[4][9][64];
  __shared__ float bmax_s[4];
  const int tid = threadIdx.x;
  if (tid < NTAO * 4) {
    int j = tid >> 2, p = tid & 3;
    float tao = life[j / 9] + (-40.0f + 10.0f * (float)(j % 9));
    float Tp = fmaxf(t[p] * ratio[p] * 1000.0f, 0.0f);
    et_s[j][p] = expf((-Tp) / tao);
  }
  if (tid < 3) inten_s[tid] = inten[tid];
  __syncthreads();

  const int blk = blockIdx.x;
  const int b = blk >> 10;
  const int hwg = blk & 1023;
  const int p = tid >> 6;
  const int lane = tid & 63;
  const int hw = hwg * 64 + lane;

  float acc = 0.0f;

  for (int c = 0; c < 3; ++c) {
    float tg9[9];
#pragma unroll
    for (int j = 0; j < 9; ++j) tg9[j] = 0.0f;

    const uint32_t e = (uint32_t)((((b * 4 + p) * 3 + c) << 16) + hw);
    float dec = decay_pc(kl0, kl1, ks0, ks1, e,
                         (const float(*)[4])&et_s[c * 9], p, tg9);
    acc = fmaf(x[e] * dec, inten_s[c], acc);

#pragma unroll
    for (int j = 0; j < 9; ++j) tg_lds[p][j][lane] = tg9[j];
    __syncthreads();
    for (int jj = p; jj < 9; jj += 4) {
      float s = ((tg_lds[0][jj][lane] + tg_lds[1][jj][lane]) +
                 (tg_lds[2][jj][lane] + tg_lds[3][jj][lane]));
      out[TAO_OFF + ((b * NTAO + c * 9 + jj) << 16) + hw] = s * 0.25f;
    }
    __syncthreads();
  }

  out[((b * 4 + p) << 16) + hw] = acc;   // x2 staged in the x4 slot

  float m = acc;
#pragma unroll
  for (int off = 32; off; off >>= 1) m = fmaxf(m, __shfl_xor(m, off));
  if (lane == 0) bmax_s[p] = m;
  __syncthreads();
  if (tid == 0)
    bmax[blk] = fmaxf(fmaxf(bmax_s[0], bmax_s[1]),
                      fmaxf(bmax_s[2], bmax_s[3]));
}

// ---------------------------------------------------------------------------
// Kernel C: 2 elements/thread, Poisson 4-task state machine (r13) with a
// tighter inner loop (running kaddr, ee recomputed only on advance) and
// single bg load (bg panel index provably equal for the e0/e1 pair).
// ---------------------------------------------------------------------------
__global__ __launch_bounds__(256) void kC(
    const float* __restrict__ bgf, const float* __restrict__ t,
    const float* __restrict__ ratio, float* __restrict__ out,
    const float* __restrict__ bmax, PCParams pc) {
  __shared__ float red_s[4];
  __shared__ float mx_s;
  __shared__ uint32_t keys_lds[2 * NPK * 2];   // [chain][i][2]
  const int tid = threadIdx.x;

  // stage poisson subkeys to LDS
  if (tid < NPK * 2) {
    keys_lds[tid] = pc.s1[tid];
    keys_lds[NPK * 2 + tid] = pc.s2[tid];
  }

  // global max from bmax[2048]
  float m = 0.0f;
#pragma unroll
  for (int k = 0; k < 8; ++k) m = fmaxf(m, bmax[tid + 256 * k]);
#pragma unroll
  for (int off = 32; off; off >>= 1) m = fmaxf(m, __shfl_xor(m, off));
  if ((tid & 63) == 0) red_s[tid >> 6] = m;
  __syncthreads();
  if (tid == 0)
    mx_s = fmaxf(fmaxf(red_s[0], red_s[1]), fmaxf(red_s[2], red_s[3]));
  __syncthreads();
  const float mx = mx_s;
  const float rmx = __builtin_amdgcn_rcpf(mx + 0.0001f);

  if (blockIdx.x == 0 && tid < 8)
    out[OUT2_OFF + tid] = (tid < 4) ? t[tid] * ratio[tid] : ratio[tid - 4];

  const int gid = blockIdx.x * 256 + tid;       // [0, 262144)
  const int e0 = gid;                           // bp in [0,4)
  const int e1 = gid + X4_SIZE / 2;             // bp in [4,8), same p & hw

  const int bp0 = e0 >> 16, bp1 = bp0 + 4;
  const int hw0 = e0 & 0xFFFF;                  // hw1 == hw0
  const int r0 = hw0 >> 8, cc0 = hw0 & 255;
  const int row0 = pc.idx + r0;
  const int pp0 = bp0 & 3;                      // pp1 == pp0 (b-dim only)

  const float x2_0 = out[e0];
  const float x2_1 = out[e1];
  const float bg0 = bgf[(pp0 * BGH + row0) * BGW + cc0];  // serves e0 AND e1

  const uint32_t ebg0 = (uint32_t)((bp0 * BGH + row0) * BGW + cc0);
  const uint32_t ebg1 = ebg0 + (uint32_t)(4 * BGH) * (uint32_t)BGW;
  float nb0 = normal_e(pc.kb0, pc.kb1, ebg0);
  float nb1 = normal_e(pc.kb0, pc.kb1, ebg1);
  float n0  = normal_e(pc.kn0, pc.kn1, (uint32_t)e0);
  float n1  = normal_e(pc.kn0, pc.kn1, (uint32_t)e1);
  float patch0 = (bg0 * pc.bg1[bp0] + nb0 * pc.bg2[bp0]) * 0.1f;
  float patch1 = (bg0 * pc.bg1[bp1] + nb1 * pc.bg2[bp1]) * 0.1f;

  const float xm0 = x2_0 * rmx;
  const float xm1 = x2_1 * rmx;
  const float T2 = 0.13533528f;                 // e^-2
  const float T1_0 = __expf(-fmaxf(xm0, 0.0f)); // lam=0 -> T=1 -> count 0
  const float T1_1 = __expf(-fmaxf(xm1, 0.0f));

  // ---- 4-task poisson state machine (bit-identical draws to r11/r13) ----
  // task t: 0:(e0,chain1) 1:(e0,chain2) 2:(e1,chain1) 3:(e1,chain2)
  int tsk = 0, i = 0;
  int kaddr = 0;                                // running LDS dword addr
  uint32_t ee = (uint32_t)e0;
  float P = 1.0f;
  float T = T1_0;
  uint32_t cnts = 0;
#pragma clang loop unroll(disable)
  for (int guard = 0; guard < 4 * NPK + 4; ++guard) {
    bool active = (tsk < 4);
    if (!__any(active)) break;
    uint32_t key0 = keys_lds[kaddr];
    uint32_t key1 = keys_lds[kaddr + 1];
    float u = u01(bits32(key0, key1, ee));
    float Pn = P * u;
    bool succ = active && (Pn > T);
    if (succ) cnts += (1u << (tsk * 8));
    bool advance = active && (!succ || i == NPK - 1);
    if (active) P = Pn;
    if (advance) {
      tsk += 1;
      i = 0;
      kaddr = (tsk & 1) ? (NPK * 2) : 0;        // chain2 base : chain1 base
      ee = (tsk < 2) ? (uint32_t)e0 : (uint32_t)e1;
      P = 1.0f;
      T = (tsk & 1) ? T2 : T1_1;
    } else if (active) {
      i += 1;
      kaddr += 2;
    }
  }

  const float pi0 = (float)(cnts & 255u);
  const float po0 = (float)((cnts >> 8) & 255u);
  const float pi1 = (float)((cnts >> 16) & 255u);
  const float po1 = (float)(cnts >> 24);

  // ---- epilogues ----
  {
    float n_int = fmaf(xm0, 5.0f, n0);
    float x3 = ((n_int + pi0) + po0) + x2_0;
    float v = x3 + patch0;
    v = fminf(fmaxf(v, 0.0f), 255.0f);
    out[e0] = v * (1.0f / 255.0f);
  }
  {
    float n_int = fmaf(xm1, 5.0f, n1);
    float x3 = ((n_int + pi1) + po1) + x2_1;
    float v = x3 + patch1;
    v = fminf(fmaxf(v, 0.0f), 255.0f);
    out[e1] = v * (1.0f / 255.0f);
  }
}

// ---------------------------------------------------------------------------
// Host
// ---------------------------------------------------------------------------
extern "C" void kernel_launch(void* const* d_in, const int* in_sizes, int n_in,
                              void* d_out, int out_size, void* d_ws, size_t ws_size,
                              hipStream_t stream) {
  const float* x     = (const float*)d_in[0];
  const float* t     = (const float*)d_in[1];
  const float* ratio = (const float*)d_in[2];
  const float* life  = (const float*)d_in[3];
  const float* inten = (const float*)d_in[4];
  const float* bgf   = (const float*)d_in[5];
  float* out = (float*)d_out;
  float* bmax = (float*)d_ws;            // [0, 2048): per-block maxes

  // key(42) = (0,42) -> 9 subkeys:
  // k_life, k_sig, k_norm, k_p1, k_p2, k_bg1, k_bg2, k_bgn, k_idx
  uint32_t sk[9][2];
  jax_split(0u, 42u, 9, sk);

  PCParams pc;
  pc.kn0 = sk[2][0]; pc.kn1 = sk[2][1];
  pc.kb0 = sk[7][0]; pc.kb1 = sk[7][1];

  {
    uint32_t r0 = sk[3][0], r1 = sk[3][1];
    for (int i = 0; i < NPK; ++i) {
      uint32_t two[2][2];
      jax_split(r0, r1, 2, two);
      pc.s1[2*i] = two[1][0]; pc.s1[2*i+1] = two[1][1];
      r0 = two[0][0]; r1 = two[0][1];
    }
    r0 = sk[4][0]; r1 = sk[4][1];
    for (int i = 0; i < NPK; ++i) {
      uint32_t two[2][2];
      jax_split(r0, r1, 2, two);
      pc.s2[2*i] = two[1][0]; pc.s2[2*i+1] = two[1][1];
      r0 = two[0][0]; r1 = two[0][1];
    }
  }

  for (uint32_t i = 0; i < 8; ++i) {
    pc.bg1[i] = u01(bits32(sk[5][0], sk[5][1], i)) * 0.5f + 0.5f;
    pc.bg2[i] = u01(bits32(sk[6][0], sk[6][1], i)) * 0.5f + 0.5f;
  }

  // idx = randint(k_idx, (), 0, 9): exact jax double-word algorithm
  {
    uint32_t hi = bits32(sk[8][0], sk[8][1], 0u);
    uint32_t lo = bits32(sk[8][0], sk[8][1], 1u);
    const uint32_t span = 9u;
    uint32_t mult = (65536u % span);
    mult = (mult * mult) % span;
    uint32_t off = ((hi % span) * mult + (lo % span)) % span;
    pc.idx = (int)off;
  }

  kA<<<NBLK_A, 256, 0, stream>>>(x, t, ratio, life, inten, out, bmax,
                                 sk[0][0], sk[0][1], sk[1][0], sk[1][1]);
  kC<<<NBLK_C, 256, 0, stream>>>(bgf, t, ratio, out, bmax, pc);
}